// Round 2
// baseline (64.352 us; speedup 1.0000x reference)
//
#include <hip/hip_runtime.h>

// BinaryTreeRNN, single fused kernel. Per row n of x (N x 16, f32):
//   h[l] = leaf_w[l,:] . x[n,:] + leaf_b[l]         (8 leaves)
//   3 tree levels (om3/w3/b3 -> om2/w2/b2 -> om1/w1/b1), each node:
//     s = l + r; out = w*(c0*s + c1*sin s + c2*cos s + c3*l*r) + b,
//     (c0..c3) = softmax(om row). Output h[0] : (N,) f32.
//
// Memory-bound: 256 MB read + 16 MB write -> ~43 us floor @ 6.3 TB/s.
// Node coefficients are folded (c_k = w * softmax_k) per-thread from
// wave-uniform scalar-loaded inputs (~70 VALU ops, far under the memory
// budget) -- avoids a second dispatch in the captured graph.

__device__ __forceinline__ float node_eval(float l, float r, const float c[5]) {
    float s = l + r;
    float sn, cs;
    sincosf(s, &sn, &cs);
    float acc = c[4];
    acc = fmaf(c[3], l * r, acc);
    acc = fmaf(c[2], cs, acc);
    acc = fmaf(c[1], sn, acc);
    acc = fmaf(c[0], s,  acc);
    return acc;
}

__global__ __launch_bounds__(256) void tree_fused(const float4* __restrict__ x,
                                                  const float* __restrict__ lw,
                                                  const float* __restrict__ lb,
                                                  const float* __restrict__ w1, const float* __restrict__ b1,
                                                  const float* __restrict__ om1,
                                                  const float* __restrict__ w2, const float* __restrict__ b2,
                                                  const float* __restrict__ om2,
                                                  const float* __restrict__ w3, const float* __restrict__ b3,
                                                  const float* __restrict__ om3,
                                                  float* __restrict__ out, int N) {
    int n = blockIdx.x * 256 + threadIdx.x;
    if (n >= N) return;

    // Folded node coefficients, computed from wave-uniform inputs.
    float cf[7][5];
#pragma unroll
    for (int nd = 0; nd < 7; ++nd) {
        const float* om;
        float w, b;
        if (nd < 4)      { om = om3 + nd * 4;       w = w3[nd];     b = b3[nd]; }
        else if (nd < 6) { om = om2 + (nd - 4) * 4; w = w2[nd - 4]; b = b2[nd - 4]; }
        else             { om = om1;                w = w1[0];      b = b1[0]; }
        float m  = fmaxf(fmaxf(om[0], om[1]), fmaxf(om[2], om[3]));
        float e0 = __expf(om[0] - m), e1 = __expf(om[1] - m);
        float e2 = __expf(om[2] - m), e3 = __expf(om[3] - m);
        float inv = w / (e0 + e1 + e2 + e3);
        cf[nd][0] = e0 * inv; cf[nd][1] = e1 * inv;
        cf[nd][2] = e2 * inv; cf[nd][3] = e3 * inv;
        cf[nd][4] = b;
    }

    // 64 B/lane contiguous read: 4 x dwordx4, fully consumed.
    const float4* xp = x + (size_t)n * 4;
    float4 a0 = xp[0], a1 = xp[1], a2 = xp[2], a3 = xp[3];
    float xv[16] = {a0.x, a0.y, a0.z, a0.w, a1.x, a1.y, a1.z, a1.w,
                    a2.x, a2.y, a2.z, a2.w, a3.x, a3.y, a3.z, a3.w};

    // 8 leaves, lw/lb are wave-uniform -> scalar loads, SGPR-operand FMAs.
    float h[8];
#pragma unroll
    for (int l = 0; l < 8; ++l) {
        float acc = lb[l];
#pragma unroll
        for (int v = 0; v < 16; ++v) acc = fmaf(lw[l * 16 + v], xv[v], acc);
        h[l] = acc;
    }

    float g4[4];
#pragma unroll
    for (int nd = 0; nd < 4; ++nd) g4[nd] = node_eval(h[2 * nd], h[2 * nd + 1], cf[nd]);
    float g2[2];
    g2[0] = node_eval(g4[0], g4[1], cf[4]);
    g2[1] = node_eval(g4[2], g4[3], cf[5]);
    out[n] = node_eval(g2[0], g2[1], cf[6]);
}

extern "C" void kernel_launch(void* const* d_in, const int* in_sizes, int n_in,
                              void* d_out, int out_size, void* d_ws, size_t ws_size,
                              hipStream_t stream) {
    const float* x      = (const float*)d_in[0];
    const float* leaf_w = (const float*)d_in[1];
    const float* leaf_b = (const float*)d_in[2];
    const float* w1     = (const float*)d_in[3];
    const float* b1     = (const float*)d_in[4];
    const float* om1    = (const float*)d_in[5];
    const float* w2     = (const float*)d_in[6];
    const float* b2     = (const float*)d_in[7];
    const float* om2    = (const float*)d_in[8];
    const float* w3     = (const float*)d_in[9];
    const float* b3     = (const float*)d_in[10];
    const float* om3    = (const float*)d_in[11];

    int N = in_sizes[0] / 16;
    int blocks = (N + 255) / 256;
    float* out = (float*)d_out;

    tree_fused<<<blocks, 256, 0, stream>>>((const float4*)x, leaf_w, leaf_b,
                                           w1, b1, om1, w2, b2, om2, w3, b3, om3,
                                           out, N);
}

// Round 3
// 50.940 us; speedup vs baseline: 1.2633x; 1.2633x over previous
//
#include <hip/hip_runtime.h>

// BinaryTreeRNN, single grid-stride kernel. Per row n of x (N x 16, f32):
//   h[l] = leaf_w[l,:] . x[n,:] + leaf_b[l]         (8 leaves)
//   3 tree levels (om3/w3/b3 -> om2/w2/b2 -> om1/w1/b1), each node:
//     s = l + r; out = w*(c0*s + c1*sin s + c2*cos s + c3*l*r) + b,
//     (c0..c3) = softmax(om row). Output h[0] : (N,) f32.
//
// Memory-bound: 256 MB read + 16 MB write -> ~43 us floor @ 6.3 TB/s.
//
// R2 lesson: per-thread coefficient folding at 1 row/thread cost ~14 us
// (VGPR pressure + 62.5k waves each paying ~28 v_exp). Fix here:
//   - grid-stride with 2048 blocks => ~8 rows/thread, setup amortized 8x
//   - readfirstlane the 35 folded coefficients into SGPRs (uniform values)
//     => SGPR-operand FMAs, low VGPR pressure, single dispatch
//   - native v_sin/v_cos with explicit mul(1/2pi)+fract reduction
//     (~10 VALU ops vs ~350 for libm sincosf; error ~|s|*2^-24 rad)

__device__ __forceinline__ float rfl(float v) {
    return __int_as_float(__builtin_amdgcn_readfirstlane(__float_as_int(v)));
}

__device__ __forceinline__ void fast_sincos(float s, float* sn, float* cs) {
#if __has_builtin(__builtin_amdgcn_sinf) && __has_builtin(__builtin_amdgcn_cosf)
    const float INV2PI = 0.15915494309189535f;
    float t = s * INV2PI;
    t = t - floorf(t);               // v_fract: exact mod-1 in revolutions
    *sn = __builtin_amdgcn_sinf(t);  // sin(t * 2pi)
    *cs = __builtin_amdgcn_cosf(t);  // cos(t * 2pi)
#else
    sincosf(s, sn, cs);
#endif
}

__device__ __forceinline__ float node_eval(float l, float r, const float c[5]) {
    float s = l + r;
    float sn, cs;
    fast_sincos(s, &sn, &cs);
    float acc = c[4];
    acc = fmaf(c[3], l * r, acc);
    acc = fmaf(c[2], cs, acc);
    acc = fmaf(c[1], sn, acc);
    acc = fmaf(c[0], s,  acc);
    return acc;
}

__global__ __launch_bounds__(256) void tree_fused(const float4* __restrict__ x,
                                                  const float* __restrict__ lw,
                                                  const float* __restrict__ lb,
                                                  const float* __restrict__ w1, const float* __restrict__ b1,
                                                  const float* __restrict__ om1,
                                                  const float* __restrict__ w2, const float* __restrict__ b2,
                                                  const float* __restrict__ om2,
                                                  const float* __restrict__ w3, const float* __restrict__ b3,
                                                  const float* __restrict__ om3,
                                                  float* __restrict__ out, int N) {
    // One-time per-thread coefficient fold (uniform inputs -> identical in all
    // lanes), then broadcast into SGPRs via readfirstlane.
    float cf[7][5];
#pragma unroll
    for (int nd = 0; nd < 7; ++nd) {
        const float* om;
        float w, b;
        if (nd < 4)      { om = om3 + nd * 4;       w = w3[nd];     b = b3[nd]; }
        else if (nd < 6) { om = om2 + (nd - 4) * 4; w = w2[nd - 4]; b = b2[nd - 4]; }
        else             { om = om1;                w = w1[0];      b = b1[0]; }
        float m  = fmaxf(fmaxf(om[0], om[1]), fmaxf(om[2], om[3]));
        float e0 = __expf(om[0] - m), e1 = __expf(om[1] - m);
        float e2 = __expf(om[2] - m), e3 = __expf(om[3] - m);
        float inv = w / (e0 + e1 + e2 + e3);
        cf[nd][0] = rfl(e0 * inv); cf[nd][1] = rfl(e1 * inv);
        cf[nd][2] = rfl(e2 * inv); cf[nd][3] = rfl(e3 * inv);
        cf[nd][4] = rfl(b);
    }

    int stride = gridDim.x * 256;
    for (int n = blockIdx.x * 256 + threadIdx.x; n < N; n += stride) {
        // 64 B/lane contiguous read: 4 x dwordx4, fully consumed.
        const float4* xp = x + (size_t)n * 4;
        float4 a0 = xp[0], a1 = xp[1], a2 = xp[2], a3 = xp[3];
        float xv[16] = {a0.x, a0.y, a0.z, a0.w, a1.x, a1.y, a1.z, a1.w,
                        a2.x, a2.y, a2.z, a2.w, a3.x, a3.y, a3.z, a3.w};

        // 8 leaves; lw/lb are uniform -> scalar loads, SGPR-operand FMAs.
        float h[8];
#pragma unroll
        for (int l = 0; l < 8; ++l) {
            float acc = lb[l];
#pragma unroll
            for (int v = 0; v < 16; ++v) acc = fmaf(lw[l * 16 + v], xv[v], acc);
            h[l] = acc;
        }

        float g4[4];
#pragma unroll
        for (int nd = 0; nd < 4; ++nd) g4[nd] = node_eval(h[2 * nd], h[2 * nd + 1], cf[nd]);
        float g2[2];
        g2[0] = node_eval(g4[0], g4[1], cf[4]);
        g2[1] = node_eval(g4[2], g4[3], cf[5]);
        out[n] = node_eval(g2[0], g2[1], cf[6]);
    }
}

extern "C" void kernel_launch(void* const* d_in, const int* in_sizes, int n_in,
                              void* d_out, int out_size, void* d_ws, size_t ws_size,
                              hipStream_t stream) {
    const float* x      = (const float*)d_in[0];
    const float* leaf_w = (const float*)d_in[1];
    const float* leaf_b = (const float*)d_in[2];
    const float* w1     = (const float*)d_in[3];
    const float* b1     = (const float*)d_in[4];
    const float* om1    = (const float*)d_in[5];
    const float* w2     = (const float*)d_in[6];
    const float* b2     = (const float*)d_in[7];
    const float* om2    = (const float*)d_in[8];
    const float* w3     = (const float*)d_in[9];
    const float* b3     = (const float*)d_in[10];
    const float* om3    = (const float*)d_in[11];

    int N = in_sizes[0] / 16;
    float* out = (float*)d_out;

    int blocks = 2048;  // 8 blocks/CU; each thread handles ~8 rows grid-stride
    tree_fused<<<blocks, 256, 0, stream>>>((const float4*)x, leaf_w, leaf_b,
                                           w1, b1, om1, w2, b2, om2, w3, b3, om3,
                                           out, N);
}